// Round 5
// baseline (255.616 us; speedup 1.0000x reference)
//
#include <hip/hip_runtime.h>

// out[b, 2n+o] = x[b,2n]*W[n,0,o] + x[b,2n+1]*W[n,1,o]
// W[n,m,o] = softmax_m(c[n,:,o]) = sigmoid(c[n,m,o] - c[n,1-m,o])
// Pure streaming: x read once (512 MiB), out written once (512 MiB).
// Shape replicates the m13 6.29 TB/s float4-copy pattern: contiguous
// grid-stride sweep, PLAIN (L2-allocating) loads/stores — no nt.
// Stride (524288 f32x4) is a multiple of the row length (2048 f32x4), so each
// thread's column chunk — and its 2x2 weight set — is loop-invariant.
#define ELI_BATCH     16384
#define ELI_LAYER_IN  8192
#define ELI_NCHUNK    (ELI_LAYER_IN / 4)            // 2048 f32x4 per row
#define ELI_NTHREADS  (2048 * 256)                  // 524288 threads
#define ELI_TOTAL4    (ELI_BATCH * ELI_NCHUNK)      // 33554432 f32x4
#define ELI_ITERS     (ELI_TOTAL4 / ELI_NTHREADS)   // 64

typedef float f32x4 __attribute__((ext_vector_type(4)));

__global__ __launch_bounds__(256, 8)
void EfficientLearnableInterconnect_33913061769291_kernel(
        const float* __restrict__ x,
        const float* __restrict__ c,
        float* __restrict__ out) {
    const int tid   = blockIdx.x * 256 + threadIdx.x;   // 0..524287
    const int chunk = tid & (ELI_NCHUNK - 1);           // constant column chunk

    // c[n] as f32x4: (c[n,0,0], c[n,0,1], c[n,1,0], c[n,1,1])
    const f32x4 c0 = ((const f32x4*)c)[2 * chunk];
    const f32x4 c1 = ((const f32x4*)c)[2 * chunk + 1];

    const float w000 = 1.f / (1.f + __expf(c0.z - c0.x));
    const float w010 = 1.f / (1.f + __expf(c0.x - c0.z));
    const float w001 = 1.f / (1.f + __expf(c0.w - c0.y));
    const float w011 = 1.f / (1.f + __expf(c0.y - c0.w));
    const float w100 = 1.f / (1.f + __expf(c1.z - c1.x));
    const float w110 = 1.f / (1.f + __expf(c1.x - c1.z));
    const float w101 = 1.f / (1.f + __expf(c1.w - c1.y));
    const float w111 = 1.f / (1.f + __expf(c1.y - c1.w));

    const f32x4* __restrict__ xp = (const f32x4*)x + tid;
    f32x4* __restrict__       op = (f32x4*)out     + tid;

    #pragma unroll 8
    for (int r = 0; r < ELI_ITERS; ++r) {
        const f32x4 v = xp[(size_t)r * ELI_NTHREADS];
        f32x4 o;
        o.x = v.x * w000 + v.y * w010;
        o.y = v.x * w001 + v.y * w011;
        o.z = v.z * w100 + v.w * w110;
        o.w = v.z * w101 + v.w * w111;
        op[(size_t)r * ELI_NTHREADS] = o;
    }
}

extern "C" void kernel_launch(void* const* d_in, const int* in_sizes, int n_in,
                              void* d_out, int out_size, void* d_ws, size_t ws_size,
                              hipStream_t stream) {
    const float* x = (const float*)d_in[0];
    const float* c = (const float*)d_in[1];
    float* out = (float*)d_out;

    const dim3 grid(ELI_NTHREADS / 256);  // 2048 blocks
    const dim3 block(256);
    EfficientLearnableInterconnect_33913061769291_kernel<<<grid, block, 0, stream>>>(x, c, out);
}

// Round 6
// 235.832 us; speedup vs baseline: 1.0839x; 1.0839x over previous
//
#include <hip/hip_runtime.h>

// out[b, 2n+o] = x[b,2n]*W[n,0,o] + x[b,2n+1]*W[n,1,o]
// W[n,m,o] = softmax_m(c[n,:,o]) = sigmoid(c[n,m,o] - c[n,1-m,o])
// Pure streaming: x read once (512 MiB), out written once (512 MiB).
// Best config so far (R3): block-column mapping + nt loads/stores = 220.5 us.
// This round: widen the per-wave load pipeline — __launch_bounds__(256,4)
// (128 VGPRs) + explicit 8-deep load batch into a register array, so 8
// global_load_dwordx4 nt are in flight before the first dependent store.
#define ELI_BATCH     16384
#define ELI_LAYER_IN  8192
#define ELI_NCHUNK    (ELI_LAYER_IN / 4)     // 2048 f32x4 per row
#define ELI_CBLOCKS   8                      // 8 blocks cover the columns
#define ELI_ROWG      256                    // row groups
#define ELI_ROWS_PG   64                     // rows per group
#define ELI_DEPTH     8                      // loads in flight per thread

typedef float f32x4 __attribute__((ext_vector_type(4)));

__global__ __launch_bounds__(256, 4)
void EfficientLearnableInterconnect_33913061769291_kernel(
        const float* __restrict__ x,
        const float* __restrict__ c,
        float* __restrict__ out) {
    const int chunk = (blockIdx.x & (ELI_CBLOCKS - 1)) * 256 + threadIdx.x; // 0..2047
    const int rowg  = blockIdx.x / ELI_CBLOCKS;                             // 0..255
    const int row0  = rowg * ELI_ROWS_PG;

    // c[n] as f32x4: (c[n,0,0], c[n,0,1], c[n,1,0], c[n,1,1])
    const f32x4 c0 = ((const f32x4*)c)[2 * chunk];
    const f32x4 c1 = ((const f32x4*)c)[2 * chunk + 1];

    const float w000 = 1.f / (1.f + __expf(c0.z - c0.x));
    const float w010 = 1.f / (1.f + __expf(c0.x - c0.z));
    const float w001 = 1.f / (1.f + __expf(c0.w - c0.y));
    const float w011 = 1.f / (1.f + __expf(c0.y - c0.w));
    const float w100 = 1.f / (1.f + __expf(c1.z - c1.x));
    const float w110 = 1.f / (1.f + __expf(c1.x - c1.z));
    const float w101 = 1.f / (1.f + __expf(c1.w - c1.y));
    const float w111 = 1.f / (1.f + __expf(c1.y - c1.w));

    const f32x4* __restrict__ xp = (const f32x4*)x + (size_t)row0 * ELI_NCHUNK + chunk;
    f32x4* __restrict__       op = (f32x4*)out     + (size_t)row0 * ELI_NCHUNK + chunk;

    for (int b = 0; b < ELI_ROWS_PG / ELI_DEPTH; ++b) {
        f32x4 v[ELI_DEPTH];
        #pragma unroll
        for (int j = 0; j < ELI_DEPTH; ++j)
            v[j] = __builtin_nontemporal_load(
                xp + (size_t)(b * ELI_DEPTH + j) * ELI_NCHUNK);
        #pragma unroll
        for (int j = 0; j < ELI_DEPTH; ++j) {
            f32x4 o;
            o.x = v[j].x * w000 + v[j].y * w010;
            o.y = v[j].x * w001 + v[j].y * w011;
            o.z = v[j].z * w100 + v[j].w * w110;
            o.w = v[j].z * w101 + v[j].w * w111;
            __builtin_nontemporal_store(
                o, op + (size_t)(b * ELI_DEPTH + j) * ELI_NCHUNK);
        }
    }
}

extern "C" void kernel_launch(void* const* d_in, const int* in_sizes, int n_in,
                              void* d_out, int out_size, void* d_ws, size_t ws_size,
                              hipStream_t stream) {
    const float* x = (const float*)d_in[0];
    const float* c = (const float*)d_in[1];
    float* out = (float*)d_out;

    const dim3 grid(ELI_CBLOCKS * ELI_ROWG);  // 2048 blocks
    const dim3 block(256);
    EfficientLearnableInterconnect_33913061769291_kernel<<<grid, block, 0, stream>>>(x, c, out);
}

// Round 7
// 223.060 us; speedup vs baseline: 1.1460x; 1.0573x over previous
//
#include <hip/hip_runtime.h>

// out[b, 2n+o] = x[b,2n]*W[n,0,o] + x[b,2n+1]*W[n,1,o]
// W[n,m,o] = softmax_m(c[n,:,o]) = sigmoid(c[n,m,o] - c[n,1-m,o])
// Pure streaming: x read once (512 MiB), out written once (512 MiB).
// R3 (best, 220.5us): block-col mapping, nt load + nt store, unroll 8, 32 waves/CU.
// This round, single-variable change vs R3: PLAIN store (L2 write-aggregation,
// like the 6.7 TB/s fill kernels) while keeping NT load (no L2 read pollution).
#define ELI_BATCH     16384
#define ELI_LAYER_IN  8192
#define ELI_NCHUNK    (ELI_LAYER_IN / 4)     // 2048 f32x4 per row
#define ELI_CBLOCKS   (ELI_NCHUNK / 256)     // 8 blocks cover the columns
#define ELI_ROWG      256                    // row groups
#define ELI_ROWS_PG   (ELI_BATCH / ELI_ROWG) // 64 rows per group

typedef float f32x4 __attribute__((ext_vector_type(4)));

__global__ __launch_bounds__(256, 8)
void EfficientLearnableInterconnect_33913061769291_kernel(
        const float* __restrict__ x,
        const float* __restrict__ c,
        float* __restrict__ out) {
    const int chunk = (blockIdx.x & (ELI_CBLOCKS - 1)) * 256 + threadIdx.x; // 0..2047
    const int rowg  = blockIdx.x / ELI_CBLOCKS;                             // 0..255
    const int row0  = rowg * ELI_ROWS_PG;

    // c[n] as f32x4: (c[n,0,0], c[n,0,1], c[n,1,0], c[n,1,1])
    const f32x4 c0 = ((const f32x4*)c)[2 * chunk];
    const f32x4 c1 = ((const f32x4*)c)[2 * chunk + 1];

    const float w000 = 1.f / (1.f + __expf(c0.z - c0.x));
    const float w010 = 1.f / (1.f + __expf(c0.x - c0.z));
    const float w001 = 1.f / (1.f + __expf(c0.w - c0.y));
    const float w011 = 1.f / (1.f + __expf(c0.y - c0.w));
    const float w100 = 1.f / (1.f + __expf(c1.z - c1.x));
    const float w110 = 1.f / (1.f + __expf(c1.x - c1.z));
    const float w101 = 1.f / (1.f + __expf(c1.w - c1.y));
    const float w111 = 1.f / (1.f + __expf(c1.y - c1.w));

    const f32x4* __restrict__ xp = (const f32x4*)x + (size_t)row0 * ELI_NCHUNK + chunk;
    f32x4* __restrict__       op = (f32x4*)out     + (size_t)row0 * ELI_NCHUNK + chunk;

    #pragma unroll 8
    for (int r = 0; r < ELI_ROWS_PG; ++r) {
        const f32x4 v = __builtin_nontemporal_load(xp);
        f32x4 o;
        o.x = v.x * w000 + v.y * w010;
        o.y = v.x * w001 + v.y * w011;
        o.z = v.z * w100 + v.w * w110;
        o.w = v.z * w101 + v.w * w111;
        *op = o;  // PLAIN store: let L2 aggregate the write stream
        xp += ELI_NCHUNK;
        op += ELI_NCHUNK;
    }
}

extern "C" void kernel_launch(void* const* d_in, const int* in_sizes, int n_in,
                              void* d_out, int out_size, void* d_ws, size_t ws_size,
                              hipStream_t stream) {
    const float* x = (const float*)d_in[0];
    const float* c = (const float*)d_in[1];
    float* out = (float*)d_out;

    const dim3 grid(ELI_CBLOCKS * ELI_ROWG);  // 2048 blocks
    const dim3 block(256);
    EfficientLearnableInterconnect_33913061769291_kernel<<<grid, block, 0, stream>>>(x, c, out);
}

// Round 8
// 209.406 us; speedup vs baseline: 1.2207x; 1.0652x over previous
//
#include <hip/hip_runtime.h>

// out[b, 2n+o] = x[b,2n]*W[n,0,o] + x[b,2n+1]*W[n,1,o]
// W[n,m,o] = softmax_m(c[n,:,o]) = sigmoid(c[n,m,o] - c[n,1-m,o])
// Pure streaming: x read once (512 MiB), out written once (512 MiB).
// R3 best = 220.5us (block-col, nt/nt, unroll 8, 32 waves/CU).
// This round: manual 2-stage software pipeline (va/vb 4-row buffers) ordered
//   load B -> store A -> load A' -> store B
// so no s_waitcnt ever has to retire a store (single vmcnt counter retires
// in issue order -> stores between load batches cause head-of-line stalls).
#define ELI_NCHUNK    2048                   // f32x4 per row
#define ELI_CBLOCKS   8                      // blocks covering columns
#define ELI_ROWG      256                    // row groups
#define ELI_ROWS_PG   64                     // rows per group

typedef float f32x4 __attribute__((ext_vector_type(4)));

#define NTL(p)     __builtin_nontemporal_load(p)
#define NTS(p, v)  __builtin_nontemporal_store((v), (p))

__global__ __launch_bounds__(256, 8)
void EfficientLearnableInterconnect_33913061769291_kernel(
        const float* __restrict__ x,
        const float* __restrict__ c,
        float* __restrict__ out) {
    const int chunk = (blockIdx.x & (ELI_CBLOCKS - 1)) * 256 + threadIdx.x; // 0..2047
    const int rowg  = blockIdx.x / ELI_CBLOCKS;                             // 0..255
    const int row0  = rowg * ELI_ROWS_PG;

    // c[n] as f32x4: (c[n,0,0], c[n,0,1], c[n,1,0], c[n,1,1])
    const f32x4 c0 = ((const f32x4*)c)[2 * chunk];
    const f32x4 c1 = ((const f32x4*)c)[2 * chunk + 1];

    const float w000 = 1.f / (1.f + __expf(c0.z - c0.x));
    const float w010 = 1.f / (1.f + __expf(c0.x - c0.z));
    const float w001 = 1.f / (1.f + __expf(c0.w - c0.y));
    const float w011 = 1.f / (1.f + __expf(c0.y - c0.w));
    const float w100 = 1.f / (1.f + __expf(c1.z - c1.x));
    const float w110 = 1.f / (1.f + __expf(c1.x - c1.z));
    const float w101 = 1.f / (1.f + __expf(c1.w - c1.y));
    const float w111 = 1.f / (1.f + __expf(c1.y - c1.w));

#define APPLY(v) ({ f32x4 _o; \
    _o.x = (v).x * w000 + (v).y * w010; \
    _o.y = (v).x * w001 + (v).y * w011; \
    _o.z = (v).z * w100 + (v).w * w110; \
    _o.w = (v).z * w101 + (v).w * w111; _o; })

    const f32x4* __restrict__ xp = (const f32x4*)x + (size_t)row0 * ELI_NCHUNK + chunk;
    f32x4* __restrict__       op = (f32x4*)out     + (size_t)row0 * ELI_NCHUNK + chunk;

    f32x4 va0, va1, va2, va3, vb0, vb1, vb2, vb3;

    // prologue: rows 0..3
    va0 = NTL(xp + 0 * ELI_NCHUNK);
    va1 = NTL(xp + 1 * ELI_NCHUNK);
    va2 = NTL(xp + 2 * ELI_NCHUNK);
    va3 = NTL(xp + 3 * ELI_NCHUNK);

    for (int g = 0; g < 7; ++g) {
        // load B: rows +4..7
        vb0 = NTL(xp + 4 * ELI_NCHUNK);
        vb1 = NTL(xp + 5 * ELI_NCHUNK);
        vb2 = NTL(xp + 6 * ELI_NCHUNK);
        vb3 = NTL(xp + 7 * ELI_NCHUNK);
        // store A: rows +0..3 (waits only on va loads, older than any live store)
        NTS(op + 0 * ELI_NCHUNK, APPLY(va0));
        NTS(op + 1 * ELI_NCHUNK, APPLY(va1));
        NTS(op + 2 * ELI_NCHUNK, APPLY(va2));
        NTS(op + 3 * ELI_NCHUNK, APPLY(va3));
        // load A': rows +8..11
        va0 = NTL(xp + 8  * ELI_NCHUNK);
        va1 = NTL(xp + 9  * ELI_NCHUNK);
        va2 = NTL(xp + 10 * ELI_NCHUNK);
        va3 = NTL(xp + 11 * ELI_NCHUNK);
        // store B: rows +4..7
        NTS(op + 4 * ELI_NCHUNK, APPLY(vb0));
        NTS(op + 5 * ELI_NCHUNK, APPLY(vb1));
        NTS(op + 6 * ELI_NCHUNK, APPLY(vb2));
        NTS(op + 7 * ELI_NCHUNK, APPLY(vb3));
        xp += 8 * ELI_NCHUNK;
        op += 8 * ELI_NCHUNK;
    }
    // epilogue: rows 56..63 (xp/op now at row 56)
    vb0 = NTL(xp + 4 * ELI_NCHUNK);
    vb1 = NTL(xp + 5 * ELI_NCHUNK);
    vb2 = NTL(xp + 6 * ELI_NCHUNK);
    vb3 = NTL(xp + 7 * ELI_NCHUNK);
    NTS(op + 0 * ELI_NCHUNK, APPLY(va0));
    NTS(op + 1 * ELI_NCHUNK, APPLY(va1));
    NTS(op + 2 * ELI_NCHUNK, APPLY(va2));
    NTS(op + 3 * ELI_NCHUNK, APPLY(va3));
    NTS(op + 4 * ELI_NCHUNK, APPLY(vb0));
    NTS(op + 5 * ELI_NCHUNK, APPLY(vb1));
    NTS(op + 6 * ELI_NCHUNK, APPLY(vb2));
    NTS(op + 7 * ELI_NCHUNK, APPLY(vb3));
#undef APPLY
}

extern "C" void kernel_launch(void* const* d_in, const int* in_sizes, int n_in,
                              void* d_out, int out_size, void* d_ws, size_t ws_size,
                              hipStream_t stream) {
    const float* x = (const float*)d_in[0];
    const float* c = (const float*)d_in[1];
    float* out = (float*)d_out;

    const dim3 grid(ELI_CBLOCKS * ELI_ROWG);  // 2048 blocks
    const dim3 block(256);
    EfficientLearnableInterconnect_33913061769291_kernel<<<grid, block, 0, stream>>>(x, c, out);
}